// Round 7
// baseline (747.523 us; speedup 1.0000x reference)
//
#include <hip/hip_runtime.h>
#include <hip/hip_fp16.h>
#include <math.h>
#include <string.h>

// ---------------- constants ----------------
constexpr int HDIM = 128;     // hidden width
constexpr int RB   = 136;     // fp16 row stride for feature buffers (272B = 17 x 16B)
constexpr float BN_INV = 0.99999500003749980f; // 1/sqrt(1+1e-5)

typedef _Float16 half8v __attribute__((ext_vector_type(8)));  // 8 fp16 (4 VGPR)
typedef __attribute__((ext_vector_type(4))) float float4v;    // MFMA accum

// packed fp16 ops on raw u32 pairs (VOP3P)
__device__ __forceinline__ unsigned pkmax(unsigned a, unsigned b) {
  unsigned r;
  asm volatile("v_pk_max_f16 %0, %1, %2" : "=v"(r) : "v"(a), "v"(b));
  return r;
}
__device__ __forceinline__ unsigned pkadd(unsigned a, unsigned b) {
  unsigned r;
  asm volatile("v_pk_add_f16 %0, %1, %2" : "=v"(r) : "v"(a), "v"(b));
  return r;
}

__device__ __forceinline__ float us2f(unsigned short u) { __half h; memcpy(&h, &u, 2); return __half2float(h); }
__device__ __forceinline__ unsigned short f2us(float f) {
  __half h = __float2half(f); unsigned short u; memcpy(&u, &h, 2); return u;
}

// monotone float<->uint encoding for atomic max on floats
__device__ __forceinline__ unsigned encf(float f) {
  unsigned u = __float_as_uint(f);
  return (u & 0x80000000u) ? ~u : (u | 0x80000000u);
}
__device__ __forceinline__ float decf(unsigned u) {
  return (u & 0x80000000u) ? __uint_as_float(u ^ 0x80000000u) : __uint_as_float(~u);
}

// ================= CSR build =================
__global__ void k_hist(const int* __restrict__ ei, int* __restrict__ deg, int E) {
  int e = blockIdx.x * blockDim.x + threadIdx.x;
  if (e < E) atomicAdd(&deg[ei[E + e]], 1);  // dst row
}

__global__ void k_scan_block(const int* __restrict__ deg, int* __restrict__ excl,
                             int* __restrict__ blockSums, int N) {
  __shared__ int s[1024];
  int tid = threadIdx.x;
  int i = blockIdx.x * 1024 + tid;
  int v = (i < N) ? deg[i] : 0;
  s[tid] = v;
  __syncthreads();
  for (int off = 1; off < 1024; off <<= 1) {
    int t = (tid >= off) ? s[tid - off] : 0;
    __syncthreads();
    s[tid] += t;
    __syncthreads();
  }
  if (i < N) excl[i] = s[tid] - v;
  if (tid == 1023) blockSums[blockIdx.x] = s[1023];
}

__global__ void k_scan_sums(int* blockSums, int NB) {
  __shared__ int s[256];
  int tid = threadIdx.x;
  int v = (tid < NB) ? blockSums[tid] : 0;
  s[tid] = v;
  __syncthreads();
  for (int off = 1; off < 256; off <<= 1) {
    int t = (tid >= off) ? s[tid - off] : 0;
    __syncthreads();
    s[tid] += t;
    __syncthreads();
  }
  if (tid < NB) blockSums[tid] = s[tid] - v; // exclusive
}

__global__ void k_scan_add(const int* __restrict__ excl, const int* __restrict__ blockOff,
                           int* __restrict__ rowptr, int N, int E) {
  int i = blockIdx.x * blockDim.x + threadIdx.x;
  if (i < N) rowptr[i] = excl[i] + blockOff[i >> 10];
  if (i == 0) rowptr[N] = E;
}

// bucket bases come straight from rowptr (bucket = contiguous node range)
__global__ void k_binit(const int* __restrict__ rowptr, int* __restrict__ bbase,
                        int* __restrict__ gcur, int nbkt, int shift, int E) {
  int b = threadIdx.x;
  if (b < nbkt) {
    int v = rowptr[b << shift];
    bbase[b] = v;
    gcur[b] = v;
  }
  if (b == 0) bbase[nbkt] = E;
}

// phase A: block-local LDS counting-sort of 4096-edge chunks by bucket,
// run-coalesced flush into per-bucket regions of `sorted` (u64 = dst<<32 | src)
__global__ __launch_bounds__(256) void k_bscatter(
    const int* __restrict__ ei, int* __restrict__ gcur,
    unsigned long long* __restrict__ sorted, int E, int shift, int nbkt) {
  __shared__ int hcnt[256];   // per-bucket count, then reused as cursor
  __shared__ int hstart[256]; // exclusive start within chunk
  __shared__ int gbase[256];  // global base for this block's run
  __shared__ unsigned long long sbuf[4096];  // 32 KB

  const int tid = threadIdx.x;
  const int base = blockIdx.x * 4096;
  const int validCount = min(4096, E - base);

  hcnt[tid] = 0;
  __syncthreads();

  int sArr[16], dArr[16];
#pragma unroll
  for (int k = 0; k < 16; ++k) {
    int e = base + k * 256 + tid;
    if (e < E) {
      sArr[k] = ei[e];
      dArr[k] = ei[E + e];
      atomicAdd(&hcnt[dArr[k] >> shift], 1);
    } else {
      sArr[k] = -1; dArr[k] = -1;
    }
  }
  __syncthreads();

  // exclusive scan of hcnt into hstart
  {
    int v = hcnt[tid];
    __shared__ int sc[256];
    sc[tid] = v;
    __syncthreads();
    for (int off = 1; off < 256; off <<= 1) {
      int t = (tid >= off) ? sc[tid - off] : 0;
      __syncthreads();
      sc[tid] += t;
      __syncthreads();
    }
    hstart[tid] = sc[tid] - v;
    if (tid < nbkt && v > 0) gbase[tid] = atomicAdd(&gcur[tid], v);
    hcnt[tid] = sc[tid] - v;  // reset as running cursor
  }
  __syncthreads();

  // scatter into LDS, compacted by bucket
#pragma unroll
  for (int k = 0; k < 16; ++k) {
    if (dArr[k] >= 0) {
      int b = dArr[k] >> shift;
      int p = atomicAdd(&hcnt[b], 1);
      sbuf[p] = ((unsigned long long)(unsigned)dArr[k] << 32) | (unsigned)sArr[k];
    }
  }
  __syncthreads();

  // coalesced copy-out of per-bucket runs
  for (int p = tid; p < validCount; p += 256) {
    unsigned long long v = sbuf[p];
    int b = (int)(v >> 32) >> shift;
    sorted[(size_t)gbase[b] + (p - hstart[b])] = v;
  }
}

// phase B: one block per bucket; scatter src into eidx with L2-local window
__global__ __launch_bounds__(256) void k_fill2(
    const unsigned long long* __restrict__ sorted, const int* __restrict__ bbase,
    const int* __restrict__ rowptr, int* __restrict__ cursor, int* __restrict__ eidx) {
  const int b = blockIdx.x;
  const int lo = bbase[b], hi = bbase[b + 1];
  for (int idx = lo + threadIdx.x; idx < hi; idx += 256) {
    unsigned long long v = sorted[idx];
    int d = (int)(v >> 32);
    int s = (int)(v & 0xFFFFFFFFu);
    int p = atomicAdd(&cursor[d], 1);
    eidx[rowptr[d] + p] = s;
  }
}

// ================= feature concat (layer 0), fp16, wave per row =================
// h0 row: 0..63 = x, 64..65 = pos, 66..127 = 0, 128..129 = pos, 130..135 = 0.
// cols 128..135 (static across layers) also written into h1buf.
__global__ __launch_bounds__(256) void k_concat0(
    const float* __restrict__ x, const float* __restrict__ pos,
    unsigned short* __restrict__ h0, unsigned short* __restrict__ h1buf, int N) {
  int r = (int)((blockIdx.x * 256 + threadIdx.x) >> 6);
  if (r >= N) return;
  int lane = threadIdx.x & 63;
  h0[(size_t)r * RB + lane] = f2us(x[(size_t)r * 64 + lane]);
  float pv = (lane < 2) ? pos[(size_t)r * 2 + lane] : 0.0f;
  h0[(size_t)r * RB + 64 + lane] = f2us(pv);
  if (lane < 8) {
    unsigned short p16 = f2us((lane < 2) ? pos[(size_t)r * 2 + lane] : 0.0f);
    h0[(size_t)r * RB + 128 + lane] = p16;
    h1buf[(size_t)r * RB + 128 + lane] = p16;
  }
}

// ================= weight prep: all 6 matrices, one kernel =================
// Wt layout: Wt1_l at l*20480 (128 x 160, k-major), Wt2_l at 61440 + l*16384 (128 x 128)
__global__ void k_prepall(const float* __restrict__ w01, const float* __restrict__ w11,
                          const float* __restrict__ w21, const float* __restrict__ w02,
                          const float* __restrict__ w12, const float* __restrict__ w22,
                          unsigned short* __restrict__ Wt) {
  int idx = blockIdx.x * blockDim.x + threadIdx.x;
  if (idx < 61440) {
    int l = idx / 20480, rem = idx % 20480;
    int n = rem / 160, k = rem % 160;
    const float* W = (l == 0) ? w01 : ((l == 1) ? w11 : w21);
    int K = (l == 0) ? 66 : 130;
    float v = (k < K) ? W[(size_t)k * 128 + n] : 0.0f;
    Wt[idx] = f2us(v);
  } else if (idx < 110592) {
    int idx2 = idx - 61440;
    int l = idx2 / 16384, rem = idx2 % 16384;
    int n = rem / 128, k = rem % 128;
    const float* W = (l == 0) ? w02 : ((l == 1) ? w12 : w22);
    Wt[idx] = f2us(W[(size_t)k * 128 + n]);
  }
}

// ================= fused GIN layer: agg (gather-max) + MLP (MFMA) =================
// Block = 256 = 4 waves; block tile = 64 nodes; wave w owns rows w*16..+15.
// Phase A: wave aggregates its own 16 rows into LDS zt (no cross-wave sharing -> NO barriers).
// Phase B: GEMM1 from zt, epilogue1 overwrites zt rows with h1 (same-wave, program order),
//          GEMM2 from zt, epilogue2 -> hout cols 0..127.
__global__ __launch_bounds__(256) void k_gin(
    const unsigned short* __restrict__ hin, const int* __restrict__ rowptr,
    const int* __restrict__ eidx,
    const unsigned short* __restrict__ Wt1, const unsigned short* __restrict__ Wt2,
    const float* __restrict__ b1, const float* __restrict__ g1, const float* __restrict__ e1,
    const float* __restrict__ b2, const float* __restrict__ g2, const float* __restrict__ e2,
    unsigned short* __restrict__ hout, int actA, int kc1, int N) {
  __shared__ __align__(16) unsigned short zt[64 * RB + 32];
  const int tid = threadIdx.x;
  const int w = tid >> 6, lane = tid & 63;
  const int half = lane >> 5, lc = lane & 31;
  const int rbase = blockIdx.x * 64 + w * 16;
  const bool act = lc < actA;
  const int cb = lc * 8;   // fp16 col base
  const unsigned NEGINF = 0xFC00FC00u;

  // pad tail after row 63 (only wave 3's kc=4 A-read overruns into it)
  if (w == 3 && lane < 32) zt[64 * RB + lane] = 0;

  // ---- phase A: aggregate 16 nodes into zt rows w*16 .. w*16+15 ----
  for (int i = 0; i < 16; ++i) {
    const int wid = rbase + i;
    unsigned m0 = NEGINF, m1 = NEGINF, m2 = NEGINF, m3 = NEGINF;
    int r0 = 0, r1 = 0;
    if (wid < N) { r0 = rowptr[wid]; r1 = rowptr[wid + 1]; }
    int e = r0 + half;
    for (; e + 2 < r1; e += 4) {   // this half handles e and e+2 (2 gathers in flight)
      int sA = eidx[e], sB = eidx[e + 2];
      if (act) {
        uint4 va = *(const uint4*)(hin + (size_t)sA * RB + cb);
        uint4 vb = *(const uint4*)(hin + (size_t)sB * RB + cb);
        m0 = pkmax(m0, pkmax(va.x, vb.x));
        m1 = pkmax(m1, pkmax(va.y, vb.y));
        m2 = pkmax(m2, pkmax(va.z, vb.z));
        m3 = pkmax(m3, pkmax(va.w, vb.w));
      }
    }
    for (; e < r1; e += 2) {
      int s = eidx[e];
      if (act) {
        uint4 va = *(const uint4*)(hin + (size_t)s * RB + cb);
        m0 = pkmax(m0, va.x);
        m1 = pkmax(m1, va.y);
        m2 = pkmax(m2, va.z);
        m3 = pkmax(m3, va.w);
      }
    }
    // combine halves
    m0 = pkmax(m0, (unsigned)__shfl_xor((int)m0, 32));
    m1 = pkmax(m1, (unsigned)__shfl_xor((int)m1, 32));
    m2 = pkmax(m2, (unsigned)__shfl_xor((int)m2, 32));
    m3 = pkmax(m3, (unsigned)__shfl_xor((int)m3, 32));

    if (half == 0 && lc < 17) {
      uint4 o = make_uint4(0u, 0u, 0u, 0u);
      if (wid < N && act) {
        if (r0 == r1) { m0 = 0u; m1 = 0u; m2 = 0u; m3 = 0u; }  // empty -> agg 0
        uint4 sv = *(const uint4*)(hin + (size_t)wid * RB + cb);
        o.x = pkadd(sv.x, m0);
        o.y = pkadd(sv.y, m1);
        o.z = pkadd(sv.z, m2);
        o.w = pkadd(sv.w, m3);
      }
      *(uint4*)(&zt[(w * 16 + i) * RB + cb]) = o;
    }
  }

  // ---- phase B: MLP (same-wave LDS dependency; compiler orders via lgkmcnt) ----
  const int arow = lane & 15;   // A row within 16-row tile; also B/D column offset
  const int grp  = lane >> 4;   // k-group (and D row group)
  const unsigned short* zrow = &zt[(w * 16 + arow) * RB];

  float4v acc[8];
#pragma unroll
  for (int i = 0; i < 8; ++i) acc[i] = (float4v){0.f, 0.f, 0.f, 0.f};

  // GEMM1 over kc1*32 (zero-padded K; Wt1 stride 160)
  for (int kc = 0; kc < kc1; ++kc) {
    half8v a = *(const half8v*)(zrow + kc * 32 + grp * 8);
    const unsigned short* wp = Wt1 + (size_t)arow * 160 + kc * 32 + grp * 8;
#pragma unroll
    for (int nt = 0; nt < 8; ++nt) {
      half8v b = *(const half8v*)(wp + (size_t)(nt * 16) * 160);
      acc[nt] = __builtin_amdgcn_mfma_f32_16x16x32_f16(a, b, acc[nt], 0, 0, 0);
    }
  }

  // epilogue 1 -> h1 overwrites this wave's zt rows (cols 0..127)
#pragma unroll
  for (int nt = 0; nt < 8; ++nt) {
    int col = nt * 16 + arow;
    float sc = g1[col] * BN_INV;
    float bb = b1[col];
    float be = e1[col];
#pragma unroll
    for (int j = 0; j < 4; ++j) {
      float v = fmaxf(fmaf(acc[nt][j] + bb, sc, be), 0.0f);
      zt[(w * 16 + grp * 4 + j) * RB + col] = f2us(v);
    }
  }

  // GEMM2: 128 x 128
#pragma unroll
  for (int i = 0; i < 8; ++i) acc[i] = (float4v){0.f, 0.f, 0.f, 0.f};
  for (int kc = 0; kc < 4; ++kc) {
    half8v a = *(const half8v*)(zrow + kc * 32 + grp * 8);
    const unsigned short* wp = Wt2 + (size_t)arow * HDIM + kc * 32 + grp * 8;
#pragma unroll
    for (int nt = 0; nt < 8; ++nt) {
      half8v b = *(const half8v*)(wp + (size_t)(nt * 16) * HDIM);
      acc[nt] = __builtin_amdgcn_mfma_f32_16x16x32_f16(a, b, acc[nt], 0, 0, 0);
    }
  }

  // epilogue 2 -> hout (cols 0..127)
#pragma unroll
  for (int nt = 0; nt < 8; ++nt) {
    int col = nt * 16 + arow;
    float sc = g2[col] * BN_INV;
    float bb = b2[col];
    float be = e2[col];
#pragma unroll
    for (int j = 0; j < 4; ++j) {
      int gr = rbase + grp * 4 + j;
      if (gr < N) {
        float v = fmaxf(fmaf(acc[nt][j] + bb, sc, be), 0.0f);
        hout[(size_t)gr * RB + col] = f2us(v);
      }
    }
  }
}

// ================= global max pool (batch sorted) =================
__global__ void k_pool_init(unsigned* pooled, int GH) {
  int i = blockIdx.x * blockDim.x + threadIdx.x;
  if (i < GH) pooled[i] = 0x007FFFFFu;  // enc(-inf)
}

__global__ __launch_bounds__(128) void k_pool(
    const unsigned short* __restrict__ hcat, const int* __restrict__ batch,
    unsigned* __restrict__ pooled, int N) {
  int base = blockIdx.x * 128;
  int c = threadIdx.x;
  int end = min(base + 128, N);
  int curg = -1;
  float m = -INFINITY;
  for (int i = base; i < end; ++i) {
    int g = batch[i];
    if (g != curg) {
      if (curg >= 0) atomicMax(&pooled[curg * HDIM + c], encf(m));
      curg = g;
      m = -INFINITY;
    }
    m = fmaxf(m, us2f(hcat[(size_t)i * RB + c]));
  }
  if (curg >= 0) atomicMax(&pooled[curg * HDIM + c], encf(m));
}

// ================= final linear [G,128] @ [128,2] =================
__global__ __launch_bounds__(64) void k_final(
    const unsigned* __restrict__ pooled, const float* __restrict__ wlin,
    const float* __restrict__ blin, float* __restrict__ out) {
  int g = blockIdx.x;
  int lane = threadIdx.x;
  float v0 = decf(pooled[g * HDIM + lane]);
  float v1 = decf(pooled[g * HDIM + 64 + lane]);
  if (v0 == -INFINITY) v0 = 0.0f;  // empty graph -> 0
  if (v1 == -INFINITY) v1 = 0.0f;
  float p0 = v0 * wlin[lane * 2 + 0] + v1 * wlin[(64 + lane) * 2 + 0];
  float p1 = v0 * wlin[lane * 2 + 1] + v1 * wlin[(64 + lane) * 2 + 1];
  for (int off = 32; off > 0; off >>= 1) {
    p0 += __shfl_down(p0, off);
    p1 += __shfl_down(p1, off);
  }
  if (lane == 0) {
    out[g * 2 + 0] = p0 + blin[0];
    out[g * 2 + 1] = p1 + blin[1];
  }
}

// ================= host launcher =================
static inline size_t ws_align(size_t x) { return (x + 511) & ~(size_t)511; }

extern "C" void kernel_launch(void* const* d_in, const int* in_sizes, int n_in,
                              void* d_out, int out_size, void* d_ws, size_t ws_size,
                              hipStream_t stream) {
  const float* x     = (const float*)d_in[0];
  const float* pos   = (const float*)d_in[1];
  const int*   ei    = (const int*)d_in[2];
  const int*   batch = (const int*)d_in[3];
  const float* wlin  = (const float*)d_in[28];
  const float* blin  = (const float*)d_in[29];

  const int N = in_sizes[3];          // batch has N elements
  const int E = in_sizes[2] / 2;
  const int G = out_size / 2;

  // bucket geometry: <=256 buckets of 2^shift nodes
  int shift = 9;
  while ((((N - 1) >> shift) + 1) > 256) ++shift;
  const int nbkt = ((N - 1) >> shift) + 1;

  // workspace layout
  char* w = (char*)d_ws;
  size_t off = 0;
  auto take = [&](size_t bytes) { void* p = w + off; off += ws_align(bytes); return p; };
  int*            deg    = (int*)take((size_t)N * 4);
  int*            cursor = (int*)take((size_t)N * 4);
  int*            rowptr = (int*)take((size_t)(N + 1) * 4);
  int*            excl   = (int*)take((size_t)N * 4);
  int*            bsums  = (int*)take(4096);
  int*            bbase  = (int*)take(2048);
  int*            gcur   = (int*)take(1024);
  int*            eidx   = (int*)take((size_t)E * 4);
  unsigned long long* sorted = (unsigned long long*)take((size_t)E * 8);
  unsigned short* hbuf0  = (unsigned short*)take((size_t)N * RB * 2 + 1024);
  unsigned short* hbuf1  = (unsigned short*)take((size_t)N * RB * 2 + 1024);
  unsigned short* Wt     = (unsigned short*)take((size_t)110592 * 2);
  unsigned*       pooled = (unsigned*)take((size_t)G * HDIM * 4);
  (void)ws_size;

  const int NB = (N + 1023) / 1024;
  const int chunks = (E + 4095) / 4096;

  // ---- build CSR by dst ----
  hipMemsetAsync(deg, 0, (size_t)N * 4, stream);
  k_hist<<<(E + 255) / 256, 256, 0, stream>>>(ei, deg, E);
  k_scan_block<<<NB, 1024, 0, stream>>>(deg, excl, bsums, N);
  k_scan_sums<<<1, 256, 0, stream>>>(bsums, NB);
  k_scan_add<<<(N + 255) / 256, 256, 0, stream>>>(excl, bsums, rowptr, N, E);
  k_binit<<<1, 256, 0, stream>>>(rowptr, bbase, gcur, nbkt, shift, E);
  k_bscatter<<<chunks, 256, 0, stream>>>(ei, gcur, sorted, E, shift, nbkt);
  hipMemsetAsync(cursor, 0, (size_t)N * 4, stream);
  k_fill2<<<nbkt, 256, 0, stream>>>(sorted, bbase, rowptr, cursor, eidx);

  // ---- layer 0 input + weights ----
  k_concat0<<<(N + 3) / 4, 256, 0, stream>>>(x, pos, hbuf0, hbuf1, N);
  k_prepall<<<(110592 + 255) / 256, 256, 0, stream>>>(
      (const float*)d_in[4], (const float*)d_in[12], (const float*)d_in[20],
      (const float*)d_in[8], (const float*)d_in[16], (const float*)d_in[24], Wt);

  // ---- 3 fused GIN layers (ping-pong buffers) ----
  const int actA[3] = {9, 17, 17};   // active 8-col groups in gather
  const int kc1a[3] = {3, 5, 5};     // GEMM1 K-chunks (x32)
  const int ginBlocks = (N + 63) / 64;
  unsigned short* hb[2] = {hbuf0, hbuf1};
  for (int l = 0; l < 3; ++l) {
    const float* b1 = (const float*)d_in[4 + l * 8 + 1];
    const float* g1 = (const float*)d_in[4 + l * 8 + 2];
    const float* e1 = (const float*)d_in[4 + l * 8 + 3];
    const float* b2 = (const float*)d_in[4 + l * 8 + 5];
    const float* g2 = (const float*)d_in[4 + l * 8 + 6];
    const float* e2 = (const float*)d_in[4 + l * 8 + 7];
    const unsigned short* Wt1 = Wt + (size_t)l * 20480;
    const unsigned short* Wt2 = Wt + 61440 + (size_t)l * 16384;
    k_gin<<<ginBlocks, 256, 0, stream>>>(hb[l & 1], rowptr, eidx, Wt1, Wt2,
                                         b1, g1, e1, b2, g2, e2,
                                         hb[(l & 1) ^ 1], actA[l], kc1a[l], N);
  }
  // layer outputs: l0 -> hbuf1, l1 -> hbuf0, l2 -> hbuf1

  // ---- pool + final linear ----
  k_pool_init<<<(G * HDIM + 255) / 256, 256, 0, stream>>>(pooled, G * HDIM);
  k_pool<<<(N + 127) / 128, 128, 0, stream>>>(hbuf1, batch, pooled, N);
  k_final<<<G, 64, 0, stream>>>(pooled, wlin, blin, (float*)d_out);
}

// Round 8
// 627.250 us; speedup vs baseline: 1.1917x; 1.1917x over previous
//
#include <hip/hip_runtime.h>
#include <hip/hip_fp16.h>
#include <math.h>
#include <string.h>

// ---------------- constants ----------------
constexpr int HDIM = 128;     // hidden width
constexpr int RB   = 136;     // fp16 row stride for hcat/z (272B = 17 x 16B)
constexpr float BN_INV = 0.99999500003749980f; // 1/sqrt(1+1e-5)

typedef _Float16 half8v __attribute__((ext_vector_type(8)));  // 8 fp16 (4 VGPR)
typedef __attribute__((ext_vector_type(4))) float float4v;    // MFMA accum

// packed fp16 ops on raw u32 pairs (VOP3P)
__device__ __forceinline__ unsigned pkmax(unsigned a, unsigned b) {
  unsigned r;
  asm volatile("v_pk_max_f16 %0, %1, %2" : "=v"(r) : "v"(a), "v"(b));
  return r;
}
__device__ __forceinline__ unsigned pkadd(unsigned a, unsigned b) {
  unsigned r;
  asm volatile("v_pk_add_f16 %0, %1, %2" : "=v"(r) : "v"(a), "v"(b));
  return r;
}

__device__ __forceinline__ float us2f(unsigned short u) { __half h; memcpy(&h, &u, 2); return __half2float(h); }
__device__ __forceinline__ unsigned short f2us(float f) {
  __half h = __float2half(f); unsigned short u; memcpy(&u, &h, 2); return u;
}

// monotone float<->uint encoding for atomic max on floats
__device__ __forceinline__ unsigned encf(float f) {
  unsigned u = __float_as_uint(f);
  return (u & 0x80000000u) ? ~u : (u | 0x80000000u);
}
__device__ __forceinline__ float decf(unsigned u) {
  return (u & 0x80000000u) ? __uint_as_float(u ^ 0x80000000u) : __uint_as_float(~u);
}

// ================= CSR build =================
__global__ void k_hist(const int* __restrict__ ei, int* __restrict__ deg, int E) {
  int e = blockIdx.x * blockDim.x + threadIdx.x;
  if (e < E) atomicAdd(&deg[ei[E + e]], 1);  // dst row
}

__global__ void k_scan_block(const int* __restrict__ deg, int* __restrict__ excl,
                             int* __restrict__ blockSums, int N) {
  __shared__ int s[1024];
  int tid = threadIdx.x;
  int i = blockIdx.x * 1024 + tid;
  int v = (i < N) ? deg[i] : 0;
  s[tid] = v;
  __syncthreads();
  for (int off = 1; off < 1024; off <<= 1) {
    int t = (tid >= off) ? s[tid - off] : 0;
    __syncthreads();
    s[tid] += t;
    __syncthreads();
  }
  if (i < N) excl[i] = s[tid] - v;
  if (tid == 1023) blockSums[blockIdx.x] = s[1023];
}

__global__ void k_scan_sums(int* blockSums, int NB) {
  __shared__ int s[256];
  int tid = threadIdx.x;
  int v = (tid < NB) ? blockSums[tid] : 0;
  s[tid] = v;
  __syncthreads();
  for (int off = 1; off < 256; off <<= 1) {
    int t = (tid >= off) ? s[tid - off] : 0;
    __syncthreads();
    s[tid] += t;
    __syncthreads();
  }
  if (tid < NB) blockSums[tid] = s[tid] - v; // exclusive
}

__global__ void k_scan_add(const int* __restrict__ excl, const int* __restrict__ blockOff,
                           int* __restrict__ rowptr, int N, int E) {
  int i = blockIdx.x * blockDim.x + threadIdx.x;
  if (i < N) rowptr[i] = excl[i] + blockOff[i >> 10];
  if (i == 0) rowptr[N] = E;
}

// bucket bases come straight from rowptr (bucket = contiguous node range)
__global__ void k_binit(const int* __restrict__ rowptr, int* __restrict__ bbase,
                        int* __restrict__ gcur, int nbkt, int shift, int E) {
  int b = threadIdx.x;
  if (b < nbkt) {
    int v = rowptr[b << shift];
    bbase[b] = v;
    gcur[b] = v;
  }
  if (b == 0) bbase[nbkt] = E;
}

// phase A: block-local LDS counting-sort of 4096-edge chunks by bucket,
// run-coalesced flush into per-bucket regions of `sorted` (u64 = dst<<32 | src)
__global__ __launch_bounds__(256) void k_bscatter(
    const int* __restrict__ ei, int* __restrict__ gcur,
    unsigned long long* __restrict__ sorted, int E, int shift, int nbkt) {
  __shared__ int hcnt[256];   // per-bucket count, then reused as cursor
  __shared__ int hstart[256]; // exclusive start within chunk
  __shared__ int gbase[256];  // global base for this block's run
  __shared__ unsigned long long sbuf[4096];  // 32 KB

  const int tid = threadIdx.x;
  const int base = blockIdx.x * 4096;
  const int validCount = min(4096, E - base);

  hcnt[tid] = 0;
  __syncthreads();

  int sArr[16], dArr[16];
#pragma unroll
  for (int k = 0; k < 16; ++k) {
    int e = base + k * 256 + tid;
    if (e < E) {
      sArr[k] = ei[e];
      dArr[k] = ei[E + e];
      atomicAdd(&hcnt[dArr[k] >> shift], 1);
    } else {
      sArr[k] = -1; dArr[k] = -1;
    }
  }
  __syncthreads();

  // exclusive scan of hcnt into hstart
  {
    int v = hcnt[tid];
    __shared__ int sc[256];
    sc[tid] = v;
    __syncthreads();
    for (int off = 1; off < 256; off <<= 1) {
      int t = (tid >= off) ? sc[tid - off] : 0;
      __syncthreads();
      sc[tid] += t;
      __syncthreads();
    }
    hstart[tid] = sc[tid] - v;
    if (tid < nbkt && v > 0) gbase[tid] = atomicAdd(&gcur[tid], v);
    hcnt[tid] = sc[tid] - v;  // reset as running cursor
  }
  __syncthreads();

  // scatter into LDS, compacted by bucket
#pragma unroll
  for (int k = 0; k < 16; ++k) {
    if (dArr[k] >= 0) {
      int b = dArr[k] >> shift;
      int p = atomicAdd(&hcnt[b], 1);
      sbuf[p] = ((unsigned long long)(unsigned)dArr[k] << 32) | (unsigned)sArr[k];
    }
  }
  __syncthreads();

  // coalesced copy-out of per-bucket runs
  for (int p = tid; p < validCount; p += 256) {
    unsigned long long v = sbuf[p];
    int b = (int)(v >> 32) >> shift;
    sorted[(size_t)gbase[b] + (p - hstart[b])] = v;
  }
}

// phase B: one block per bucket; scatter src into eidx with L2-local window
__global__ __launch_bounds__(256) void k_fill2(
    const unsigned long long* __restrict__ sorted, const int* __restrict__ bbase,
    const int* __restrict__ rowptr, int* __restrict__ cursor, int* __restrict__ eidx) {
  const int b = blockIdx.x;
  const int lo = bbase[b], hi = bbase[b + 1];
  for (int idx = lo + threadIdx.x; idx < hi; idx += 256) {
    unsigned long long v = sorted[idx];
    int d = (int)(v >> 32);
    int s = (int)(v & 0xFFFFFFFFu);
    int p = atomicAdd(&cursor[d], 1);
    eidx[rowptr[d] + p] = s;
  }
}

// ================= feature concat (layer 0), fp16, wave per row =================
// hcat row: 0..63 = x, 64..65 = pos, 66..127 = 0, 128..129 = pos, 130..135 = 0.
__global__ __launch_bounds__(256) void k_concat0(
    const float* __restrict__ x, const float* __restrict__ pos,
    unsigned short* __restrict__ h0, int N) {
  int r = (int)((blockIdx.x * 256 + threadIdx.x) >> 6);
  if (r >= N) return;
  int lane = threadIdx.x & 63;
  h0[(size_t)r * RB + lane] = f2us(x[(size_t)r * 64 + lane]);
  float pv = (lane < 2) ? pos[(size_t)r * 2 + lane] : 0.0f;
  h0[(size_t)r * RB + 64 + lane] = f2us(pv);
  if (lane < 8) {
    h0[(size_t)r * RB + 128 + lane] = f2us((lane < 2) ? pos[(size_t)r * 2 + lane] : 0.0f);
  }
}

// ================= weight prep: all 6 matrices, one kernel =================
// Wt layout: Wt1_l at l*20480 (128 x 160, k-major), Wt2_l at 61440 + l*16384 (128 x 128)
__global__ void k_prepall(const float* __restrict__ w01, const float* __restrict__ w11,
                          const float* __restrict__ w21, const float* __restrict__ w02,
                          const float* __restrict__ w12, const float* __restrict__ w22,
                          unsigned short* __restrict__ Wt) {
  int idx = blockIdx.x * blockDim.x + threadIdx.x;
  if (idx < 61440) {
    int l = idx / 20480, rem = idx % 20480;
    int n = rem / 160, k = rem % 160;
    const float* W = (l == 0) ? w01 : ((l == 1) ? w11 : w21);
    int K = (l == 0) ? 66 : 130;
    float v = (k < K) ? W[(size_t)k * 128 + n] : 0.0f;
    Wt[idx] = f2us(v);
  } else if (idx < 110592) {
    int idx2 = idx - 61440;
    int l = idx2 / 16384, rem = idx2 % 16384;
    int n = rem / 128, k = rem % 128;
    const float* W = (l == 0) ? w02 : ((l == 1) ? w12 : w22);
    Wt[idx] = f2us(W[(size_t)k * 128 + n]);
  }
}

// ================= neighbor max aggregation (fp16, packed v_pk_max_f16) =================
// z = hcat + max_{src->i} hcat[src].  One wave per node; halves process alternate edges.
// Lane lc (0..16) covers fp16 cols lc*8..lc*8+7 (one 16B load per edge).
__global__ __launch_bounds__(256) void k_agg(
    const unsigned short* __restrict__ hcat, const int* __restrict__ rowptr,
    const int* __restrict__ eidx, unsigned short* __restrict__ z, int actA, int N) {
  int wid = (int)((blockIdx.x * 256 + threadIdx.x) >> 6);
  if (wid >= N) return;
  const int lane = threadIdx.x & 63;
  const int half = lane >> 5;
  const int lc = lane & 31;
  const bool act = (lc < actA) | (lc == 16);
  const int cb = lc * 8;   // fp16 col base

  const unsigned NEGINF = 0xFC00FC00u;  // (-inf, -inf) fp16
  unsigned m0 = NEGINF, m1 = NEGINF, m2 = NEGINF, m3 = NEGINF;

  int r0 = rowptr[wid], r1 = rowptr[wid + 1];
  int e = r0 + half;
  for (; e + 2 < r1; e += 4) {   // this half handles e and e+2 (2 gathers in flight)
    int sA = eidx[e], sB = eidx[e + 2];
    if (act) {
      uint4 va = *(const uint4*)(hcat + (size_t)sA * RB + cb);
      uint4 vb = *(const uint4*)(hcat + (size_t)sB * RB + cb);
      m0 = pkmax(m0, pkmax(va.x, vb.x));
      m1 = pkmax(m1, pkmax(va.y, vb.y));
      m2 = pkmax(m2, pkmax(va.z, vb.z));
      m3 = pkmax(m3, pkmax(va.w, vb.w));
    }
  }
  for (; e < r1; e += 2) {
    int s = eidx[e];
    if (act) {
      uint4 va = *(const uint4*)(hcat + (size_t)s * RB + cb);
      m0 = pkmax(m0, va.x);
      m1 = pkmax(m1, va.y);
      m2 = pkmax(m2, va.z);
      m3 = pkmax(m3, va.w);
    }
  }

  // combine the two halves
  m0 = pkmax(m0, (unsigned)__shfl_xor((int)m0, 32));
  m1 = pkmax(m1, (unsigned)__shfl_xor((int)m1, 32));
  m2 = pkmax(m2, (unsigned)__shfl_xor((int)m2, 32));
  m3 = pkmax(m3, (unsigned)__shfl_xor((int)m3, 32));

  if (half == 0 && act) {
    if (r0 == r1) { m0 = 0u; m1 = 0u; m2 = 0u; m3 = 0u; }  // empty neighborhood -> 0
    uint4 sv = *(const uint4*)(hcat + (size_t)wid * RB + cb);
    uint4 o;
    o.x = pkadd(sv.x, m0);
    o.y = pkadd(sv.y, m1);
    o.z = pkadd(sv.z, m2);
    o.w = pkadd(sv.w, m3);
    *(uint4*)(z + (size_t)wid * RB + cb) = o;
  }
}

// ================= fused MFMA MLP (fp16 in, f32 accum) =================
// Block = 256 threads = 4 waves; block tile = 64 rows; wave w owns rows w*16..+16.
__global__ __launch_bounds__(256) void k_mlp(
    const unsigned short* __restrict__ z, int Kpad1, int kc1,
    const unsigned short* __restrict__ Wt1,
    const float* __restrict__ b1, const float* __restrict__ g1, const float* __restrict__ e1,
    const unsigned short* __restrict__ Wt2,
    const float* __restrict__ b2, const float* __restrict__ g2, const float* __restrict__ e2,
    unsigned short* __restrict__ out, int N) {
  const int tid = threadIdx.x;
  const int w = tid >> 6, l = tid & 63;
  const int arow = l & 15;     // A row within 16-row tile; also B/D column offset
  const int grp  = l >> 4;     // k-group (and D row group)
  const int row0 = blockIdx.x * 64 + w * 16;

  __shared__ unsigned short h1[4][16][RB];   // per-wave h1 tile

  int zr = row0 + arow;
  if (zr >= N) zr = N - 1;                   // clamp: reads in-bounds; writes guarded
  const unsigned short* zp = z + (size_t)zr * RB + grp * 8;

  float4v acc[8];
#pragma unroll
  for (int i = 0; i < 8; ++i) acc[i] = (float4v){0.f, 0.f, 0.f, 0.f};

  // ---- GEMM1: rows x Kpad1 (zero-padded K; pad weights are 0) ----
  for (int kc = 0; kc < kc1; ++kc) {
    half8v a = *(const half8v*)(zp + kc * 32);
    const unsigned short* wp = Wt1 + (size_t)arow * Kpad1 + kc * 32 + grp * 8;
#pragma unroll
    for (int nt = 0; nt < 8; ++nt) {
      half8v b = *(const half8v*)(wp + (size_t)(nt * 16) * Kpad1);
      acc[nt] = __builtin_amdgcn_mfma_f32_16x16x32_f16(a, b, acc[nt], 0, 0, 0);
    }
  }

  // ---- epilogue 1 -> h1 (fp16, LDS; same-wave producer/consumer) ----
#pragma unroll
  for (int nt = 0; nt < 8; ++nt) {
    int col = nt * 16 + arow;
    float sc = g1[col] * BN_INV;
    float bb = b1[col];
    float be = e1[col];
#pragma unroll
    for (int j = 0; j < 4; ++j) {
      float v = fmaxf(fmaf(acc[nt][j] + bb, sc, be), 0.0f);
      h1[w][grp * 4 + j][col] = f2us(v);
    }
  }

  // ---- GEMM2: 128 x 128 ----
#pragma unroll
  for (int i = 0; i < 8; ++i) acc[i] = (float4v){0.f, 0.f, 0.f, 0.f};
  for (int kc = 0; kc < 4; ++kc) {
    half8v a = *(const half8v*)(&h1[w][arow][kc * 32 + grp * 8]);
    const unsigned short* wp = Wt2 + (size_t)arow * HDIM + kc * 32 + grp * 8;
#pragma unroll
    for (int nt = 0; nt < 8; ++nt) {
      half8v b = *(const half8v*)(wp + (size_t)(nt * 16) * HDIM);
      acc[nt] = __builtin_amdgcn_mfma_f32_16x16x32_f16(a, b, acc[nt], 0, 0, 0);
    }
  }

  // ---- epilogue 2 -> global fp16 (cols 0..127) ----
#pragma unroll
  for (int nt = 0; nt < 8; ++nt) {
    int col = nt * 16 + arow;
    float sc = g2[col] * BN_INV;
    float bb = b2[col];
    float be = e2[col];
#pragma unroll
    for (int j = 0; j < 4; ++j) {
      int gr = row0 + grp * 4 + j;
      if (gr < N) {
        float v = fmaxf(fmaf(acc[nt][j] + bb, sc, be), 0.0f);
        out[(size_t)gr * RB + col] = f2us(v);
      }
    }
  }
}

// ================= global max pool (batch sorted) =================
__global__ void k_pool_init(unsigned* pooled, int GH) {
  int i = blockIdx.x * blockDim.x + threadIdx.x;
  if (i < GH) pooled[i] = 0x007FFFFFu;  // enc(-inf)
}

__global__ __launch_bounds__(128) void k_pool(
    const unsigned short* __restrict__ hcat, const int* __restrict__ batch,
    unsigned* __restrict__ pooled, int N) {
  int base = blockIdx.x * 128;
  int c = threadIdx.x;
  int end = min(base + 128, N);
  int curg = -1;
  float m = -INFINITY;
  for (int i = base; i < end; ++i) {
    int g = batch[i];
    if (g != curg) {
      if (curg >= 0) atomicMax(&pooled[curg * HDIM + c], encf(m));
      curg = g;
      m = -INFINITY;
    }
    m = fmaxf(m, us2f(hcat[(size_t)i * RB + c]));
  }
  if (curg >= 0) atomicMax(&pooled[curg * HDIM + c], encf(m));
}

// ================= final linear [G,128] @ [128,2] =================
__global__ __launch_bounds__(64) void k_final(
    const unsigned* __restrict__ pooled, const float* __restrict__ wlin,
    const float* __restrict__ blin, float* __restrict__ out) {
  int g = blockIdx.x;
  int lane = threadIdx.x;
  float v0 = decf(pooled[g * HDIM + lane]);
  float v1 = decf(pooled[g * HDIM + 64 + lane]);
  if (v0 == -INFINITY) v0 = 0.0f;  // empty graph -> 0
  if (v1 == -INFINITY) v1 = 0.0f;
  float p0 = v0 * wlin[lane * 2 + 0] + v1 * wlin[(64 + lane) * 2 + 0];
  float p1 = v0 * wlin[lane * 2 + 1] + v1 * wlin[(64 + lane) * 2 + 1];
  for (int off = 32; off > 0; off >>= 1) {
    p0 += __shfl_down(p0, off);
    p1 += __shfl_down(p1, off);
  }
  if (lane == 0) {
    out[g * 2 + 0] = p0 + blin[0];
    out[g * 2 + 1] = p1 + blin[1];
  }
}

// ================= host launcher =================
static inline size_t ws_align(size_t x) { return (x + 511) & ~(size_t)511; }

extern "C" void kernel_launch(void* const* d_in, const int* in_sizes, int n_in,
                              void* d_out, int out_size, void* d_ws, size_t ws_size,
                              hipStream_t stream) {
  const float* x     = (const float*)d_in[0];
  const float* pos   = (const float*)d_in[1];
  const int*   ei    = (const int*)d_in[2];
  const int*   batch = (const int*)d_in[3];
  const float* wlin  = (const float*)d_in[28];
  const float* blin  = (const float*)d_in[29];

  const int N = in_sizes[3];          // batch has N elements
  const int E = in_sizes[2] / 2;
  const int G = out_size / 2;

  // bucket geometry: <=256 buckets of 2^shift nodes
  int shift = 9;
  while ((((N - 1) >> shift) + 1) > 256) ++shift;
  const int nbkt = ((N - 1) >> shift) + 1;

  // workspace layout
  char* w = (char*)d_ws;
  size_t off = 0;
  auto take = [&](size_t bytes) { void* p = w + off; off += ws_align(bytes); return p; };
  int*            deg    = (int*)take((size_t)N * 4);
  int*            cursor = (int*)take((size_t)N * 4);
  int*            rowptr = (int*)take((size_t)(N + 1) * 4);
  int*            excl   = (int*)take((size_t)N * 4);
  int*            bsums  = (int*)take(4096);
  int*            bbase  = (int*)take(2048);
  int*            gcur   = (int*)take(1024);
  int*            eidx   = (int*)take((size_t)E * 4);
  unsigned long long* sorted = (unsigned long long*)take((size_t)E * 8);
  unsigned short* hcat   = (unsigned short*)take((size_t)N * RB * 2 + 1024);
  unsigned short* z      = (unsigned short*)take((size_t)N * RB * 2 + 1024);
  unsigned short* Wt     = (unsigned short*)take((size_t)110592 * 2);
  unsigned*       pooled = (unsigned*)take((size_t)G * HDIM * 4);
  (void)ws_size;

  const int NB = (N + 1023) / 1024;
  const int chunks = (E + 4095) / 4096;

  // ---- build CSR by dst (bucketed two-phase, write-locality) ----
  hipMemsetAsync(deg, 0, (size_t)N * 4, stream);
  k_hist<<<(E + 255) / 256, 256, 0, stream>>>(ei, deg, E);
  k_scan_block<<<NB, 1024, 0, stream>>>(deg, excl, bsums, N);
  k_scan_sums<<<1, 256, 0, stream>>>(bsums, NB);
  k_scan_add<<<(N + 255) / 256, 256, 0, stream>>>(excl, bsums, rowptr, N, E);
  k_binit<<<1, 256, 0, stream>>>(rowptr, bbase, gcur, nbkt, shift, E);
  k_bscatter<<<chunks, 256, 0, stream>>>(ei, gcur, sorted, E, shift, nbkt);
  hipMemsetAsync(cursor, 0, (size_t)N * 4, stream);
  k_fill2<<<nbkt, 256, 0, stream>>>(sorted, bbase, rowptr, cursor, eidx);

  // ---- layer 0 input; z zeroed once (pad cols stay valid across layers) ----
  hipMemsetAsync(z, 0, (size_t)N * RB * 2 + 1024, stream);
  k_concat0<<<(N + 3) / 4, 256, 0, stream>>>(x, pos, hcat, N);
  k_prepall<<<(110592 + 255) / 256, 256, 0, stream>>>(
      (const float*)d_in[4], (const float*)d_in[12], (const float*)d_in[20],
      (const float*)d_in[8], (const float*)d_in[16], (const float*)d_in[24], Wt);

  const int actA[3]  = {9, 17, 17};      // active 8-col lane groups in k_agg
  const int kpad1[3] = {96, 160, 160};   // GEMM1 K padded (Wt1 stride is 160)
  const int aggBlocks = (N + 3) / 4;     // 4 waves (nodes) per 256-thread block
  const int mlpBlocks = (N + 63) / 64;

  for (int l = 0; l < 3; ++l) {
    const float* b1 = (const float*)d_in[4 + l * 8 + 1];
    const float* g1 = (const float*)d_in[4 + l * 8 + 2];
    const float* e1 = (const float*)d_in[4 + l * 8 + 3];
    const float* b2 = (const float*)d_in[4 + l * 8 + 5];
    const float* g2 = (const float*)d_in[4 + l * 8 + 6];
    const float* e2 = (const float*)d_in[4 + l * 8 + 7];
    const unsigned short* Wt1 = Wt + (size_t)l * 20480;
    const unsigned short* Wt2 = Wt + 61440 + (size_t)l * 16384;

    k_agg<<<aggBlocks, 256, 0, stream>>>(hcat, rowptr, eidx, z, actA[l], N);
    // NOTE: Wt1 stride is 160; kc1 = kpad/32 iterations read z cols up to 159
    // (over-read lands in next row / slack; matching Wt1 rows are zero).
    k_mlp<<<mlpBlocks, 256, 0, stream>>>(z, 160, kpad1[l] / 32, Wt1, b1, g1, e1,
                                         Wt2, b2, g2, e2, hcat, N);
  }

  // ---- pool + final linear ----
  k_pool_init<<<(G * HDIM + 255) / 256, 256, 0, stream>>>(pooled, G * HDIM);
  k_pool<<<(N + 127) / 128, 128, 0, stream>>>(hcat, batch, pooled, N);
  k_final<<<G, 64, 0, stream>>>(pooled, wlin, blin, (float*)d_out);
}

// Round 9
// 541.760 us; speedup vs baseline: 1.3798x; 1.1578x over previous
//
#include <hip/hip_runtime.h>
#include <hip/hip_fp16.h>
#include <math.h>
#include <string.h>

// ---------------- constants ----------------
constexpr int HDIM = 128;     // hidden width
constexpr int RB   = 136;     // fp16 row stride for hcat/z (272B = 17 x 16B)
constexpr int ZS   = 168;     // LDS z-tile stride (fp16): 336B -> bank-friendly
constexpr float BN_INV = 0.99999500003749980f; // 1/sqrt(1+1e-5)

typedef _Float16 half8v __attribute__((ext_vector_type(8)));  // 8 fp16 (4 VGPR)
typedef __attribute__((ext_vector_type(4))) float float4v;    // MFMA accum

// packed fp16 ops on raw u32 pairs (VOP3P)
__device__ __forceinline__ unsigned pkmax(unsigned a, unsigned b) {
  unsigned r;
  asm volatile("v_pk_max_f16 %0, %1, %2" : "=v"(r) : "v"(a), "v"(b));
  return r;
}
__device__ __forceinline__ unsigned pkadd(unsigned a, unsigned b) {
  unsigned r;
  asm volatile("v_pk_add_f16 %0, %1, %2" : "=v"(r) : "v"(a), "v"(b));
  return r;
}

__device__ __forceinline__ float us2f(unsigned short u) { __half h; memcpy(&h, &u, 2); return __half2float(h); }
__device__ __forceinline__ unsigned short f2us(float f) {
  __half h = __float2half(f); unsigned short u; memcpy(&u, &h, 2); return u;
}

// monotone float<->uint encoding for atomic max on floats
__device__ __forceinline__ unsigned encf(float f) {
  unsigned u = __float_as_uint(f);
  return (u & 0x80000000u) ? ~u : (u | 0x80000000u);
}
__device__ __forceinline__ float decf(unsigned u) {
  return (u & 0x80000000u) ? __uint_as_float(u ^ 0x80000000u) : __uint_as_float(~u);
}

// ================= CSR build (bucket-local, LDS-atomic version) =================
// 1) bucket histogram (LDS-staged)
__global__ __launch_bounds__(256) void k_bcnt(
    const int* __restrict__ ei, int* __restrict__ bcnt, int E, int shift, int nbkt) {
  __shared__ int hb[256];
  const int tid = threadIdx.x;
  hb[tid] = 0;
  __syncthreads();
  const int base = blockIdx.x * 4096;
#pragma unroll
  for (int k = 0; k < 16; ++k) {
    int e = base + k * 256 + tid;
    if (e < E) atomicAdd(&hb[ei[E + e] >> shift], 1);
  }
  __syncthreads();
  if (tid < nbkt && hb[tid] > 0) atomicAdd(&bcnt[tid], hb[tid]);
}

// 2) bucket exclusive scan -> bbase[0..nbkt], gcur
__global__ __launch_bounds__(256) void k_bscan(
    const int* __restrict__ bcnt, int* __restrict__ bbase, int* __restrict__ gcur,
    int nbkt, int E) {
  __shared__ int s[256];
  int tid = threadIdx.x;
  int v = (tid < nbkt) ? bcnt[tid] : 0;
  s[tid] = v;
  __syncthreads();
  for (int off = 1; off < 256; off <<= 1) {
    int t = (tid >= off) ? s[tid - off] : 0;
    __syncthreads();
    s[tid] += t;
    __syncthreads();
  }
  if (tid < nbkt) {
    int e = s[tid] - v;
    bbase[tid] = e;
    gcur[tid] = e;
  }
  if (tid == 0) bbase[nbkt] = E;
}

// 3) phase A: block-local LDS counting-sort of 4096-edge chunks by bucket,
//    run-coalesced flush into per-bucket regions of `sorted` (u64 = dst<<32 | src)
__global__ __launch_bounds__(256) void k_bscatter(
    const int* __restrict__ ei, int* __restrict__ gcur,
    unsigned long long* __restrict__ sorted, int E, int shift, int nbkt) {
  __shared__ int hcnt[256];   // per-bucket count, then reused as cursor
  __shared__ int hstart[256]; // exclusive start within chunk
  __shared__ int gbase[256];  // global base for this block's run
  __shared__ unsigned long long sbuf[4096];  // 32 KB

  const int tid = threadIdx.x;
  const int base = blockIdx.x * 4096;
  const int validCount = min(4096, E - base);

  hcnt[tid] = 0;
  __syncthreads();

  int sArr[16], dArr[16];
#pragma unroll
  for (int k = 0; k < 16; ++k) {
    int e = base + k * 256 + tid;
    if (e < E) {
      sArr[k] = ei[e];
      dArr[k] = ei[E + e];
      atomicAdd(&hcnt[dArr[k] >> shift], 1);
    } else {
      sArr[k] = -1; dArr[k] = -1;
    }
  }
  __syncthreads();

  // exclusive scan of hcnt into hstart
  {
    int v = hcnt[tid];
    __shared__ int sc[256];
    sc[tid] = v;
    __syncthreads();
    for (int off = 1; off < 256; off <<= 1) {
      int t = (tid >= off) ? sc[tid - off] : 0;
      __syncthreads();
      sc[tid] += t;
      __syncthreads();
    }
    hstart[tid] = sc[tid] - v;
    if (tid < nbkt && v > 0) gbase[tid] = atomicAdd(&gcur[tid], v);
    hcnt[tid] = sc[tid] - v;  // reset as running cursor
  }
  __syncthreads();

  // scatter into LDS, compacted by bucket
#pragma unroll
  for (int k = 0; k < 16; ++k) {
    if (dArr[k] >= 0) {
      int b = dArr[k] >> shift;
      int p = atomicAdd(&hcnt[b], 1);
      sbuf[p] = ((unsigned long long)(unsigned)dArr[k] << 32) | (unsigned)sArr[k];
    }
  }
  __syncthreads();

  // coalesced copy-out of per-bucket runs
  for (int p = tid; p < validCount; p += 256) {
    unsigned long long v = sbuf[p];
    int b = (int)(v >> 32) >> shift;
    sorted[(size_t)gbase[b] + (p - hstart[b])] = v;
  }
}

// 4) phase B: one block per bucket -> rowptr (via LDS hist+scan) + eidx scatter.
//    All cursor atomics in LDS; global reads/writes confined to bucket windows.
__global__ __launch_bounds__(256) void k_bcsr(
    const unsigned long long* __restrict__ sorted, const int* __restrict__ bbase,
    int* __restrict__ rowptr, int* __restrict__ eidx,
    int shift, int nbkt, int N, int E) {
  __shared__ int cnt[512];
  __shared__ int excl[512];
  __shared__ int sc[256];
  const int b = blockIdx.x, tid = threadIdx.x;
  const int nodeBase = b << shift;
  const int nodesHere = min(512, N - nodeBase);
  const int lo = bbase[b], hi = bbase[b + 1];

  cnt[tid] = 0; cnt[tid + 256] = 0;
  __syncthreads();
  for (int i = lo + tid; i < hi; i += 256) {
    int d = (int)(sorted[i] >> 32);
    atomicAdd(&cnt[d - nodeBase], 1);
  }
  __syncthreads();
  // pair-wise exclusive scan of 512 counters with 256 threads
  int a0 = cnt[2 * tid], a1 = cnt[2 * tid + 1];
  int pv = a0 + a1;
  sc[tid] = pv;
  __syncthreads();
  for (int off = 1; off < 256; off <<= 1) {
    int t = (tid >= off) ? sc[tid - off] : 0;
    __syncthreads();
    sc[tid] += t;
    __syncthreads();
  }
  int pe = sc[tid] - pv;
  excl[2 * tid] = pe;
  excl[2 * tid + 1] = pe + a0;
  __syncthreads();
  // rowptr + reset LDS cursors
  for (int i = tid; i < 512; i += 256) {
    if (i < nodesHere) rowptr[nodeBase + i] = lo + excl[i];
    cnt[i] = excl[i];
  }
  if (b == nbkt - 1 && tid == 0) rowptr[N] = E;
  __syncthreads();
  // scatter src into eidx
  for (int i = lo + tid; i < hi; i += 256) {
    unsigned long long v = sorted[i];
    int d = (int)(v >> 32);
    int s = (int)(v & 0xFFFFFFFFu);
    int p = atomicAdd(&cnt[d - nodeBase], 1);
    eidx[lo + p] = s;
  }
}

// ================= feature concat (layer 0), fp16, wave per row =================
// hcat row: 0..63 = x, 64..65 = pos, 66..127 = 0, 128..129 = pos, 130..135 = 0.
__global__ __launch_bounds__(256) void k_concat0(
    const float* __restrict__ x, const float* __restrict__ pos,
    unsigned short* __restrict__ h0, int N) {
  int r = (int)((blockIdx.x * 256 + threadIdx.x) >> 6);
  if (r >= N) return;
  int lane = threadIdx.x & 63;
  h0[(size_t)r * RB + lane] = f2us(x[(size_t)r * 64 + lane]);
  float pv = (lane < 2) ? pos[(size_t)r * 2 + lane] : 0.0f;
  h0[(size_t)r * RB + 64 + lane] = f2us(pv);
  if (lane < 8) {
    h0[(size_t)r * RB + 128 + lane] = f2us((lane < 2) ? pos[(size_t)r * 2 + lane] : 0.0f);
  }
}

// ================= weight prep: all 6 matrices, one kernel =================
// Wt layout: Wt1_l at l*20480 (128 x 160, k-major), Wt2_l at 61440 + l*16384 (128 x 128)
__global__ void k_prepall(const float* __restrict__ w01, const float* __restrict__ w11,
                          const float* __restrict__ w21, const float* __restrict__ w02,
                          const float* __restrict__ w12, const float* __restrict__ w22,
                          unsigned short* __restrict__ Wt) {
  int idx = blockIdx.x * blockDim.x + threadIdx.x;
  if (idx < 61440) {
    int l = idx / 20480, rem = idx % 20480;
    int n = rem / 160, k = rem % 160;
    const float* W = (l == 0) ? w01 : ((l == 1) ? w11 : w21);
    int K = (l == 0) ? 66 : 130;
    float v = (k < K) ? W[(size_t)k * 128 + n] : 0.0f;
    Wt[idx] = f2us(v);
  } else if (idx < 110592) {
    int idx2 = idx - 61440;
    int l = idx2 / 16384, rem = idx2 % 16384;
    int n = rem / 128, k = rem % 128;
    const float* W = (l == 0) ? w02 : ((l == 1) ? w12 : w22);
    Wt[idx] = f2us(W[(size_t)k * 128 + n]);
  }
}

// ================= neighbor max aggregation (fp16, packed v_pk_max_f16) =================
// z = hcat + max_{src->i} hcat[src].  One wave per node; halves process alternate edges.
// Lane lc covers fp16 cols lc*8..lc*8+7. Active: lc < actA, plus lc==16 iff doTail
// (layer 0: cols 128+ never consumed; layer 2: z[128..] reuses layer 1's pos+maxpos).
__global__ __launch_bounds__(256) void k_agg(
    const unsigned short* __restrict__ hcat, const int* __restrict__ rowptr,
    const int* __restrict__ eidx, unsigned short* __restrict__ z,
    int actA, int doTail, int N) {
  int wid = (int)((blockIdx.x * 256 + threadIdx.x) >> 6);
  if (wid >= N) return;
  const int lane = threadIdx.x & 63;
  const int half = lane >> 5;
  const int lc = lane & 31;
  const bool act = (lc < actA) || (doTail && lc == 16);
  const int cb = lc * 8;   // fp16 col base

  const unsigned NEGINF = 0xFC00FC00u;  // (-inf, -inf) fp16
  unsigned m0 = NEGINF, m1 = NEGINF, m2 = NEGINF, m3 = NEGINF;

  int r0 = rowptr[wid], r1 = rowptr[wid + 1];
  int e = r0 + half;
  for (; e + 2 < r1; e += 4) {   // this half handles e and e+2 (2 gathers in flight)
    int sA = eidx[e], sB = eidx[e + 2];
    if (act) {
      uint4 va = *(const uint4*)(hcat + (size_t)sA * RB + cb);
      uint4 vb = *(const uint4*)(hcat + (size_t)sB * RB + cb);
      m0 = pkmax(m0, pkmax(va.x, vb.x));
      m1 = pkmax(m1, pkmax(va.y, vb.y));
      m2 = pkmax(m2, pkmax(va.z, vb.z));
      m3 = pkmax(m3, pkmax(va.w, vb.w));
    }
  }
  for (; e < r1; e += 2) {
    int s = eidx[e];
    if (act) {
      uint4 va = *(const uint4*)(hcat + (size_t)s * RB + cb);
      m0 = pkmax(m0, va.x);
      m1 = pkmax(m1, va.y);
      m2 = pkmax(m2, va.z);
      m3 = pkmax(m3, va.w);
    }
  }

  // combine the two halves
  m0 = pkmax(m0, (unsigned)__shfl_xor((int)m0, 32));
  m1 = pkmax(m1, (unsigned)__shfl_xor((int)m1, 32));
  m2 = pkmax(m2, (unsigned)__shfl_xor((int)m2, 32));
  m3 = pkmax(m3, (unsigned)__shfl_xor((int)m3, 32));

  if (half == 0 && act) {
    if (r0 == r1) { m0 = 0u; m1 = 0u; m2 = 0u; m3 = 0u; }  // empty neighborhood -> 0
    uint4 sv = *(const uint4*)(hcat + (size_t)wid * RB + cb);
    uint4 o;
    o.x = pkadd(sv.x, m0);
    o.y = pkadd(sv.y, m1);
    o.z = pkadd(sv.z, m2);
    o.w = pkadd(sv.w, m3);
    *(uint4*)(z + (size_t)wid * RB + cb) = o;
  }
}

// ================= fused MFMA MLP (fp16 in, f32 accum) =================
// Block = 256 = 4 waves; wave w owns rows w*16..+15 (no barriers anywhere).
// z tile staged into LDS with coalesced uint4 loads (cols 136..159 zeroed);
// h1 epilogue overwrites the same LDS tile (same-wave data dependency).
__global__ __launch_bounds__(256) void k_mlp(
    const unsigned short* __restrict__ z, int kc1,
    const unsigned short* __restrict__ Wt1,
    const float* __restrict__ b1, const float* __restrict__ g1, const float* __restrict__ e1,
    const unsigned short* __restrict__ Wt2,
    const float* __restrict__ b2, const float* __restrict__ g2, const float* __restrict__ e2,
    unsigned short* __restrict__ out, int N) {
  __shared__ __align__(16) unsigned short zs[4][16][ZS];
  const int tid = threadIdx.x;
  const int w = tid >> 6, lane = tid & 63;
  const int arow = lane & 15;   // A row within 16-row tile; also B/D column offset
  const int grp  = lane >> 4;   // k-group (and D row group)
  const int row0 = blockIdx.x * 64 + w * 16;

  // stage this wave's 16 z-rows: 21 x 16B chunks per row (17 real + 4 zero)
  for (int c = lane; c < 16 * 21; c += 64) {
    int r = c / 21, seg = c - r * 21;
    uint4 v = make_uint4(0u, 0u, 0u, 0u);
    if (seg < 17) {
      int gr = row0 + r;
      if (gr >= N) gr = N - 1;   // clamp: reads in-bounds; writes guarded below
      v = *(const uint4*)(z + (size_t)gr * RB + seg * 8);
    }
    *(uint4*)(&zs[w][r][seg * 8]) = v;
  }

  float4v acc[8];
#pragma unroll
  for (int i = 0; i < 8; ++i) acc[i] = (float4v){0.f, 0.f, 0.f, 0.f};

  // ---- GEMM1: kc1*32 wide (zero-padded K; Wt1 stride 160) ----
  for (int kc = 0; kc < kc1; ++kc) {
    half8v a = *(const half8v*)(&zs[w][arow][kc * 32 + grp * 8]);
    const unsigned short* wp = Wt1 + (size_t)arow * 160 + kc * 32 + grp * 8;
#pragma unroll
    for (int nt = 0; nt < 8; ++nt) {
      half8v b = *(const half8v*)(wp + (size_t)(nt * 16) * 160);
      acc[nt] = __builtin_amdgcn_mfma_f32_16x16x32_f16(a, b, acc[nt], 0, 0, 0);
    }
  }

  // ---- epilogue 1 -> h1 overwrites zs (cols 0..127; same-wave producer/consumer) ----
#pragma unroll
  for (int nt = 0; nt < 8; ++nt) {
    int col = nt * 16 + arow;
    float sc = g1[col] * BN_INV;
    float bb = b1[col];
    float be = e1[col];
#pragma unroll
    for (int j = 0; j < 4; ++j) {
      float v = fmaxf(fmaf(acc[nt][j] + bb, sc, be), 0.0f);
      zs[w][grp * 4 + j][col] = f2us(v);
    }
  }

  // ---- GEMM2: 128 x 128 ----
#pragma unroll
  for (int i = 0; i < 8; ++i) acc[i] = (float4v){0.f, 0.f, 0.f, 0.f};
  for (int kc = 0; kc < 4; ++kc) {
    half8v a = *(const half8v*)(&zs[w][arow][kc * 32 + grp * 8]);
    const unsigned short* wp = Wt2 + (size_t)arow * HDIM + kc * 32 + grp * 8;
#pragma unroll
    for (int nt = 0; nt < 8; ++nt) {
      half8v b = *(const half8v*)(wp + (size_t)(nt * 16) * HDIM);
      acc[nt] = __builtin_amdgcn_mfma_f32_16x16x32_f16(a, b, acc[nt], 0, 0, 0);
    }
  }

  // ---- epilogue 2 -> global fp16 (cols 0..127) ----
#pragma unroll
  for (int nt = 0; nt < 8; ++nt) {
    int col = nt * 16 + arow;
    float sc = g2[col] * BN_INV;
    float bb = b2[col];
    float be = e2[col];
#pragma unroll
    for (int j = 0; j < 4; ++j) {
      int gr = row0 + grp * 4 + j;
      if (gr < N) {
        float v = fmaxf(fmaf(acc[nt][j] + bb, sc, be), 0.0f);
        out[(size_t)gr * RB + col] = f2us(v);
      }
    }
  }
}

// ================= global max pool (batch sorted) =================
__global__ void k_pool_init(unsigned* pooled, int GH) {
  int i = blockIdx.x * blockDim.x + threadIdx.x;
  if (i < GH) pooled[i] = 0x007FFFFFu;  // enc(-inf)
}

__global__ __launch_bounds__(128) void k_pool(
    const unsigned short* __restrict__ hcat, const int* __restrict__ batch,
    unsigned* __restrict__ pooled, int N) {
  int base = blockIdx.x * 128;
  int c = threadIdx.x;
  int end = min(base + 128, N);
  int curg = -1;
  float m = -INFINITY;
  for (int i = base; i < end; ++i) {
    int g = batch[i];
    if (g != curg) {
      if (curg >= 0) atomicMax(&pooled[curg * HDIM + c], encf(m));
      curg = g;
      m = -INFINITY;
    }
    m = fmaxf(m, us2f(hcat[(size_t)i * RB + c]));
  }
  if (curg >= 0) atomicMax(&pooled[curg * HDIM + c], encf(m));
}

// ================= final linear [G,128] @ [128,2] =================
__global__ __launch_bounds__(64) void k_final(
    const unsigned* __restrict__ pooled, const float* __restrict__ wlin,
    const float* __restrict__ blin, float* __restrict__ out) {
  int g = blockIdx.x;
  int lane = threadIdx.x;
  float v0 = decf(pooled[g * HDIM + lane]);
  float v1 = decf(pooled[g * HDIM + 64 + lane]);
  if (v0 == -INFINITY) v0 = 0.0f;  // empty graph -> 0
  if (v1 == -INFINITY) v1 = 0.0f;
  float p0 = v0 * wlin[lane * 2 + 0] + v1 * wlin[(64 + lane) * 2 + 0];
  float p1 = v0 * wlin[lane * 2 + 1] + v1 * wlin[(64 + lane) * 2 + 1];
  for (int off = 32; off > 0; off >>= 1) {
    p0 += __shfl_down(p0, off);
    p1 += __shfl_down(p1, off);
  }
  if (lane == 0) {
    out[g * 2 + 0] = p0 + blin[0];
    out[g * 2 + 1] = p1 + blin[1];
  }
}

// ================= host launcher =================
static inline size_t ws_align(size_t x) { return (x + 511) & ~(size_t)511; }

extern "C" void kernel_launch(void* const* d_in, const int* in_sizes, int n_in,
                              void* d_out, int out_size, void* d_ws, size_t ws_size,
                              hipStream_t stream) {
  const float* x     = (const float*)d_in[0];
  const float* pos   = (const float*)d_in[1];
  const int*   ei    = (const int*)d_in[2];
  const int*   batch = (const int*)d_in[3];
  const float* wlin  = (const float*)d_in[28];
  const float* blin  = (const float*)d_in[29];

  const int N = in_sizes[3];          // batch has N elements
  const int E = in_sizes[2] / 2;
  const int G = out_size / 2;

  // bucket geometry: <=256 buckets of 2^shift nodes (bcsr assumes <=512 nodes/bucket)
  int shift = 9;
  while ((((N - 1) >> shift) + 1) > 256) ++shift;
  const int nbkt = ((N - 1) >> shift) + 1;

  // workspace layout
  char* w = (char*)d_ws;
  size_t off = 0;
  auto take = [&](size_t bytes) { void* p = w + off; off += ws_align(bytes); return p; };
  int*            rowptr = (int*)take((size_t)(N + 1) * 4);
  int*            bcnt   = (int*)take(1024);
  int*            bbase  = (int*)take(2048);
  int*            gcur   = (int*)take(1024);
  int*            eidx   = (int*)take((size_t)E * 4);
  unsigned long long* sorted = (unsigned long long*)take((size_t)E * 8);
  unsigned short* hcat   = (unsigned short*)take((size_t)N * RB * 2 + 1024);
  unsigned short* z      = (unsigned short*)take((size_t)N * RB * 2 + 1024);
  unsigned short* Wt     = (unsigned short*)take((size_t)110592 * 2);
  unsigned*       pooled = (unsigned*)take((size_t)G * HDIM * 4);
  (void)ws_size;

  const int chunks = (E + 4095) / 4096;

  // ---- build CSR by dst (bucketed, all cursors in LDS) ----
  hipMemsetAsync(bcnt, 0, 1024, stream);
  k_bcnt<<<chunks, 256, 0, stream>>>(ei, bcnt, E, shift, nbkt);
  k_bscan<<<1, 256, 0, stream>>>(bcnt, bbase, gcur, nbkt, E);
  k_bscatter<<<chunks, 256, 0, stream>>>(ei, gcur, sorted, E, shift, nbkt);
  k_bcsr<<<nbkt, 256, 0, stream>>>(sorted, bbase, rowptr, eidx, shift, nbkt, N, E);

  // ---- layer 0 input; z zeroed every call (pad cols must be 0) ----
  hipMemsetAsync(z, 0, (size_t)N * RB * 2 + 1024, stream);
  k_concat0<<<(N + 3) / 4, 256, 0, stream>>>(x, pos, hcat, N);
  k_prepall<<<(110592 + 255) / 256, 256, 0, stream>>>(
      (const float*)d_in[4], (const float*)d_in[12], (const float*)d_in[20],
      (const float*)d_in[8], (const float*)d_in[16], (const float*)d_in[24], Wt);

  // layer 0: gather cols 0..71 only (K=66; cols 128+ never consumed by GEMM1).
  // layer 1: gather cols 0..127 + tail 128..135 (pos+maxpos written to z).
  // layer 2: gather cols 0..127; z[128..135] reused from layer 1 (layer-invariant).
  const int actA[3]   = {9, 16, 16};
  const int doTail[3] = {0, 1, 0};
  const int kc1a[3]   = {3, 5, 5};
  const int aggBlocks = (N + 3) / 4;     // 4 waves (nodes) per 256-thread block
  const int mlpBlocks = (N + 63) / 64;

  for (int l = 0; l < 3; ++l) {
    const float* b1 = (const float*)d_in[4 + l * 8 + 1];
    const float* g1 = (const float*)d_in[4 + l * 8 + 2];
    const float* e1 = (const float*)d_in[4 + l * 8 + 3];
    const float* b2 = (const float*)d_in[4 + l * 8 + 5];
    const float* g2 = (const float*)d_in[4 + l * 8 + 6];
    const float* e2 = (const float*)d_in[4 + l * 8 + 7];
    const unsigned short* Wt1 = Wt + (size_t)l * 20480;
    const unsigned short* Wt2 = Wt + 61440 + (size_t)l * 16384;

    k_agg<<<aggBlocks, 256, 0, stream>>>(hcat, rowptr, eidx, z, actA[l], doTail[l], N);
    k_mlp<<<mlpBlocks, 256, 0, stream>>>(z, kc1a[l], Wt1, b1, g1, e1,
                                         Wt2, b2, g2, e2, hcat, N);
  }

  // ---- pool + final linear ----
  k_pool_init<<<(G * HDIM + 255) / 256, 256, 0, stream>>>(pooled, G * HDIM);
  k_pool<<<(N + 127) / 128, 128, 0, stream>>>(hcat, batch, pooled, N);
  k_final<<<G, 64, 0, stream>>>(pooled, wlin, blin, (float*)d_out);
}